// Round 1
// baseline (161.585 us; speedup 1.0000x reference)
//
#include <hip/hip_runtime.h>
#include <math.h>

#define BB 8
#define NN 1024
#define MM 128
#define FOUT 64
#define HIDN 128

// ---------------- workspace layout (floats) ----------------
#define OFF_H       0                       // B*N*64 = 524288
#define OFF_HMA     524288                  // B*M*64 = 65536
#define OFF_HA1     589824                  // B*N
#define OFF_HA2     598016                  // B*N
#define OFF_HAM1    606208                  // B*N
#define OFF_HMAAM2  614400                  // B*M
#define OFF_RMASK   615424                  // B*N (ints)
#define OFF_WAM3    623616                  // 16
#define OFF_HPRIME  623632                  // B*N*128 = 1048576
// total ~1,672,208 floats ~ 6.7 MB

// ================= Kernel 1: h, h_ma, per-row dots, row_mask, wam3 ==========
__global__ __launch_bounds__(256) void k1_prep(
    const float* __restrict__ x, const float* __restrict__ y,
    const int* __restrict__ op_ma_adj,
    const float* __restrict__ w_op, const float* __restrict__ w_ma,
    const float* __restrict__ w_edge,
    const float* __restrict__ att_op, const float* __restrict__ att_ma,
    float* __restrict__ h, float* __restrict__ h_ma,
    float* __restrict__ ha1, float* __restrict__ ha2, float* __restrict__ ham1,
    float* __restrict__ hmaam2, int* __restrict__ rmask, float* __restrict__ wam3)
{
    __shared__ float wlds[64 * 64];
    int bid = blockIdx.x;
    int t = threadIdx.x;
    int lane = t & 63;
    int wv = t >> 6;

    if (bid < 2048) {
        for (int k = t; k < 4096; k += 256) wlds[k] = w_op[k];
        __syncthreads();
        int row = bid * 4 + wv;                 // b*N + n, 0..8191
        float xv = x[(size_t)row * 64 + lane];
        float acc = 0.f;
        #pragma unroll
        for (int i = 0; i < 64; ++i) {
            float xi = __shfl(xv, i);
            acc += xi * wlds[i * 64 + lane];
        }
        h[(size_t)row * 64 + lane] = acc;
        float d1 = acc * att_op[lane];          // a1
        float d2 = acc * att_op[64 + lane];     // a2
        float d3 = acc * att_ma[lane];          // am1
        #pragma unroll
        for (int m = 32; m; m >>= 1) {
            d1 += __shfl_xor(d1, m);
            d2 += __shfl_xor(d2, m);
            d3 += __shfl_xor(d3, m);
        }
        int v0 = op_ma_adj[(size_t)row * 128 + lane];
        int v1 = op_ma_adj[(size_t)row * 128 + 64 + lane];
        unsigned long long any = __ballot((v0 != 0) || (v1 != 0));
        if (lane == 0) {
            ha1[row] = d1; ha2[row] = d2; ham1[row] = d3;
            rmask[row] = (any == 0ULL) ? 1 : 0;
        }
    } else if (bid < 2048 + 256) {
        for (int k = t; k < 4096; k += 256) wlds[k] = w_ma[k];
        __syncthreads();
        int row = (bid - 2048) * 4 + wv;        // b*M + m, 0..1023
        float yv = y[(size_t)row * 64 + lane];
        float acc = 0.f;
        #pragma unroll
        for (int i = 0; i < 64; ++i) {
            float yi = __shfl(yv, i);
            acc += yi * wlds[i * 64 + lane];
        }
        h_ma[(size_t)row * 64 + lane] = acc;
        float d = acc * att_ma[64 + lane];      // am2
        #pragma unroll
        for (int m = 32; m; m >>= 1) d += __shfl_xor(d, m);
        if (lane == 0) hmaam2[row] = d;
    } else {
        if (t < 16) {
            float s = 0.f;
            for (int o = 0; o < 64; ++o) s += w_edge[t * 64 + o] * att_ma[128 + o];
            wam3[t] = s;
        }
    }
}

// ================= Kernel 2: op attention + h_prime_op ======================
// block = 256 threads, one block per (b, 8-row tile). LDS: 8x1032 f32.
__global__ __launch_bounds__(256) void k2_opatt(
    const int* __restrict__ op_adj, const int* __restrict__ ma_adj,
    const float* __restrict__ h, const float* __restrict__ ha1,
    const float* __restrict__ ha2, const int* __restrict__ rmask,
    float* __restrict__ h_prime)
{
    __shared__ float smem[8 * 1032];
    __shared__ float denom[8];
    int bid = blockIdx.x;
    int b = bid >> 7;
    int i0 = (bid & 127) * 8;
    int t = threadIdx.x;
    const int* opb = op_adj + (size_t)b * NN * NN;
    const int* mab = ma_adj + (size_t)b * NN * NN;

    // phase 1a: column sums (transposed reads, 8-wide coalesced segments)
    {
        int ii = t & 7, jg = t >> 3;            // jg 0..31
        int i = i0 + ii;
        int* cs = (int*)smem;
        #pragma unroll 4
        for (int it = 0; it < 32; ++it) {
            int j = jg + 32 * it;
            cs[ii * 1032 + j] = opb[(size_t)j * NN + i] + mab[(size_t)j * NN + i];
        }
    }
    __syncthreads();

    // phase 1b: masked e, per-row max/sumexp, store unnormalized exp in LDS
    int ii = t >> 5, l = t & 31;
    int i = i0 + ii;
    float ha2i = ha2[b * NN + i];
    int rm = rmask[b * NN + i];
    float e[32];
    {
        int* cs = (int*)smem;
        #pragma unroll
        for (int it = 0; it < 32; ++it) {
            int j = l + 32 * it;
            int tot = opb[(size_t)i * NN + j] + mab[(size_t)i * NN + j]
                    + cs[ii * 1032 + j];
            float ev = ha2i + ha1[b * NN + j];
            ev = ev > 0.f ? ev : 0.01f * ev;
            e[it] = (rm || tot > 0) ? ev : -INFINITY;
        }
    }
    float mx = -INFINITY;
    #pragma unroll
    for (int it = 0; it < 32; ++it) mx = fmaxf(mx, e[it]);
    #pragma unroll
    for (int msk = 16; msk; msk >>= 1) mx = fmaxf(mx, __shfl_xor(mx, msk));
    float s = 0.f;
    #pragma unroll
    for (int it = 0; it < 32; ++it) {
        float u = __expf(e[it] - mx);
        smem[ii * 1032 + l + 32 * it] = u;
        s += u;
    }
    #pragma unroll
    for (int msk = 16; msk; msk >>= 1) s += __shfl_xor(s, msk);
    if (l == 0) denom[ii] = s;
    __syncthreads();

    // phase 2: h_prime_op[ii][o] = sum_j u[ii][j] * h[b][j][o]
    {
        int wv = t >> 6, o = t & 63;
        float acc[8];
        #pragma unroll
        for (int k = 0; k < 8; ++k) acc[k] = 0.f;
        const float* hb = h + (size_t)b * NN * 64;
        for (int j = wv * 256; j < wv * 256 + 256; ++j) {
            float hv = hb[(size_t)j * 64 + o];
            #pragma unroll
            for (int k = 0; k < 8; ++k) acc[k] += smem[k * 1032 + j] * hv;
        }
        __syncthreads();            // everyone done reading u
        #pragma unroll
        for (int k = 0; k < 8; ++k) smem[(wv * 8 + k) * 64 + o] = acc[k];
        __syncthreads();
        int oo = t & 63;
        int k0 = t >> 6;            // handles rows k0 and k0+4
        for (int kk = k0; kk < 8; kk += 4) {
            float v = smem[kk * 64 + oo] + smem[(8 + kk) * 64 + oo]
                    + smem[(16 + kk) * 64 + oo] + smem[(24 + kk) * 64 + oo];
            v /= denom[kk];
            h_prime[((size_t)(b * NN + i0 + kk)) * 128 + oo] = v;
        }
    }
}

// ================= Kernel 3: ma attention + h_prime_ma ======================
// block = 128 threads (thread = m), one block per (b,n).
__global__ __launch_bounds__(128) void k3_maatt(
    const float* __restrict__ z, const int* __restrict__ op_ma_adj,
    const float* __restrict__ h, const float* __restrict__ h_ma,
    const float* __restrict__ ham1, const float* __restrict__ hmaam2,
    const int* __restrict__ rmask, const float* __restrict__ wam3,
    const float* __restrict__ w_edge, float* __restrict__ h_prime)
{
    int bid = blockIdx.x;       // b*N + n
    int t = threadIdx.x;        // m
    int wv = t >> 6;
    int b = bid >> 10;
    __shared__ float wam3s[16];
    __shared__ float red[2];
    __shared__ float zpart[2][16];
    __shared__ float zsum[16];
    __shared__ float u_lds[128];
    __shared__ float hmp[2][64];
    if (t < 16) wam3s[t] = wam3[t];
    __syncthreads();

    size_t zbase = ((size_t)bid * 128 + t) * 16;
    float4 z0 = *(const float4*)(z + zbase);
    float4 z1 = *(const float4*)(z + zbase + 4);
    float4 z2 = *(const float4*)(z + zbase + 8);
    float4 z3 = *(const float4*)(z + zbase + 12);
    float zv[16] = {z0.x,z0.y,z0.z,z0.w, z1.x,z1.y,z1.z,z1.w,
                    z2.x,z2.y,z2.z,z2.w, z3.x,z3.y,z3.z,z3.w};

    float e = ham1[bid] + hmaam2[b * 128 + t];
    #pragma unroll
    for (int i = 0; i < 16; ++i) e += zv[i] * wam3s[i];
    e = e > 0.f ? e : 0.01f * e;
    int valid = rmask[bid] || (op_ma_adj[(size_t)bid * 128 + t] > 0);
    e = valid ? e : -INFINITY;

    // max over 128
    float mx = e;
    #pragma unroll
    for (int msk = 32; msk; msk >>= 1) mx = fmaxf(mx, __shfl_xor(mx, msk));
    if ((t & 63) == 0) red[wv] = mx;
    __syncthreads();
    mx = fmaxf(red[0], red[1]);
    float u = __expf(e - mx);
    u_lds[t] = u;
    float s = u;
    #pragma unroll
    for (int msk = 32; msk; msk >>= 1) s += __shfl_xor(s, msk);
    __syncthreads();
    if ((t & 63) == 0) red[wv] = s;
    __syncthreads();
    float rden = 1.f / (red[0] + red[1]);

    // weighted z sum (16 components)
    #pragma unroll
    for (int i = 0; i < 16; ++i) {
        float v = u * zv[i];
        #pragma unroll
        for (int msk = 32; msk; msk >>= 1) v += __shfl_xor(v, msk);
        if ((t & 63) == 0) zpart[wv][i] = v;
    }
    __syncthreads();
    if (t < 16) zsum[t] = zpart[0][t] + zpart[1][t];
    __syncthreads();

    // weighted h_ma sum: wave wv handles m in [64wv, 64wv+64)
    int o = t & 63;
    float acc = 0.f;
    const float* hmb = h_ma + (size_t)b * 128 * 64;
    for (int k = 0; k < 64; ++k) {
        int m = wv * 64 + k;
        acc += u_lds[m] * hmb[(size_t)m * 64 + o];
    }
    hmp[wv][o] = acc;
    __syncthreads();

    if (t < 64) {
        float he = 0.f;
        #pragma unroll
        for (int i = 0; i < 16; ++i) he += zsum[i] * w_edge[i * 64 + t];
        float val = (hmp[0][t] + hmp[1][t] + he) * rden + h[(size_t)bid * 64 + t];
        h_prime[(size_t)bid * 128 + 64 + t] = val;
    }
}

// ================= Kernel 4: MLP + final mask ===============================
// block = 256 (4 waves), each wave does 4 rows; lane o holds cols o and o+64.
__global__ __launch_bounds__(256) void k4_mlp(
    const float* __restrict__ hp, const int* __restrict__ rmask,
    const float* __restrict__ w1, const float* __restrict__ b1,
    const float* __restrict__ w2, const float* __restrict__ b2,
    const float* __restrict__ wo, const float* __restrict__ bo,
    float* __restrict__ out)
{
    int t = threadIdx.x, wv = t >> 6, o = t & 63;
    int row0 = blockIdx.x * 16 + wv * 4;

    float inlo[4], inhi[4];
    #pragma unroll
    for (int r = 0; r < 4; ++r) {
        inlo[r] = hp[(size_t)(row0 + r) * 128 + o];
        inhi[r] = hp[(size_t)(row0 + r) * 128 + 64 + o];
    }
    // ---- layer 1 ----
    float t1lo[4], t1hi[4];
    {
        float blo = b1[o], bhi = b1[64 + o];
        #pragma unroll
        for (int r = 0; r < 4; ++r) { t1lo[r] = blo; t1hi[r] = bhi; }
        for (int i = 0; i < 64; ++i) {
            float wl = w1[i * 128 + o], wh = w1[i * 128 + 64 + o];
            #pragma unroll
            for (int r = 0; r < 4; ++r) {
                float xi = __shfl(inlo[r], i);
                t1lo[r] += xi * wl; t1hi[r] += xi * wh;
            }
        }
        for (int i = 0; i < 64; ++i) {
            float wl = w1[(64 + i) * 128 + o], wh = w1[(64 + i) * 128 + 64 + o];
            #pragma unroll
            for (int r = 0; r < 4; ++r) {
                float xi = __shfl(inhi[r], i);
                t1lo[r] += xi * wl; t1hi[r] += xi * wh;
            }
        }
        #pragma unroll
        for (int r = 0; r < 4; ++r) {
            t1lo[r] = t1lo[r] > 0.f ? t1lo[r] : __expf(t1lo[r]) - 1.f;
            t1hi[r] = t1hi[r] > 0.f ? t1hi[r] : __expf(t1hi[r]) - 1.f;
        }
    }
    // ---- layer 2 ----
    float t2lo[4], t2hi[4];
    {
        float blo = b2[o], bhi = b2[64 + o];
        #pragma unroll
        for (int r = 0; r < 4; ++r) { t2lo[r] = blo; t2hi[r] = bhi; }
        for (int i = 0; i < 64; ++i) {
            float wl = w2[i * 128 + o], wh = w2[i * 128 + 64 + o];
            #pragma unroll
            for (int r = 0; r < 4; ++r) {
                float xi = __shfl(t1lo[r], i);
                t2lo[r] += xi * wl; t2hi[r] += xi * wh;
            }
        }
        for (int i = 0; i < 64; ++i) {
            float wl = w2[(64 + i) * 128 + o], wh = w2[(64 + i) * 128 + 64 + o];
            #pragma unroll
            for (int r = 0; r < 4; ++r) {
                float xi = __shfl(t1hi[r], i);
                t2lo[r] += xi * wl; t2hi[r] += xi * wh;
            }
        }
        #pragma unroll
        for (int r = 0; r < 4; ++r) {
            t2lo[r] = t2lo[r] > 0.f ? t2lo[r] : __expf(t2lo[r]) - 1.f;
            t2hi[r] = t2hi[r] > 0.f ? t2hi[r] : __expf(t2hi[r]) - 1.f;
        }
    }
    // ---- output layer ----
    float acc[4];
    {
        float bov = bo[o];
        #pragma unroll
        for (int r = 0; r < 4; ++r) acc[r] = bov;
        for (int i = 0; i < 64; ++i) {
            float wl = wo[i * 64 + o];
            #pragma unroll
            for (int r = 0; r < 4; ++r) acc[r] += __shfl(t2lo[r], i) * wl;
        }
        for (int i = 0; i < 64; ++i) {
            float wl = wo[(64 + i) * 64 + o];
            #pragma unroll
            for (int r = 0; r < 4; ++r) acc[r] += __shfl(t2hi[r], i) * wl;
        }
    }
    #pragma unroll
    for (int r = 0; r < 4; ++r) {
        int row = row0 + r;
        float v = rmask[row] ? 0.f : acc[r];
        out[(size_t)row * 64 + o] = v;
    }
}

// ============================ launch ========================================
extern "C" void kernel_launch(void* const* d_in, const int* in_sizes, int n_in,
                              void* d_out, int out_size, void* d_ws, size_t ws_size,
                              hipStream_t stream) {
    const float* x      = (const float*)d_in[0];
    const float* y      = (const float*)d_in[1];
    const float* z      = (const float*)d_in[2];
    const int*   op_adj = (const int*)d_in[3];
    const int*   ma_adj = (const int*)d_in[4];
    const int*   opma   = (const int*)d_in[5];
    const float* w_op   = (const float*)d_in[6];
    const float* w_ma   = (const float*)d_in[7];
    const float* w_edge = (const float*)d_in[8];
    const float* att_op = (const float*)d_in[9];
    const float* att_ma = (const float*)d_in[10];
    const float* w1     = (const float*)d_in[11];
    const float* b1     = (const float*)d_in[12];
    const float* w2     = (const float*)d_in[13];
    const float* b2     = (const float*)d_in[14];
    const float* wo     = (const float*)d_in[15];
    const float* bo     = (const float*)d_in[16];
    float* out = (float*)d_out;

    float* ws = (float*)d_ws;
    float* h       = ws + OFF_H;
    float* h_ma    = ws + OFF_HMA;
    float* ha1     = ws + OFF_HA1;
    float* ha2     = ws + OFF_HA2;
    float* ham1    = ws + OFF_HAM1;
    float* hmaam2  = ws + OFF_HMAAM2;
    int*   rmask   = (int*)(ws + OFF_RMASK);
    float* wam3    = ws + OFF_WAM3;
    float* h_prime = ws + OFF_HPRIME;

    k1_prep<<<2048 + 256 + 1, 256, 0, stream>>>(
        x, y, opma, w_op, w_ma, w_edge, att_op, att_ma,
        h, h_ma, ha1, ha2, ham1, hmaam2, rmask, wam3);

    k2_opatt<<<1024, 256, 0, stream>>>(
        op_adj, ma_adj, h, ha1, ha2, rmask, h_prime);

    k3_maatt<<<8192, 128, 0, stream>>>(
        z, opma, h, h_ma, ham1, hmaam2, rmask, wam3, w_edge, h_prime);

    k4_mlp<<<512, 256, 0, stream>>>(
        h_prime, rmask, w1, b1, w2, b2, wo, bo, out);
}

// Round 2
// 116.381 us; speedup vs baseline: 1.3884x; 1.3884x over previous
//
#include <hip/hip_runtime.h>
#include <math.h>

#define BB 8
#define NN 1024
#define MM 128
#define FOUT 64
#define HIDN 128

// ---------------- workspace layout (floats) ----------------
#define OFF_H       0                       // B*N*64 = 524288
#define OFF_HMA     524288                  // B*M*64 = 65536
#define OFF_HA1     589824                  // B*N
#define OFF_HA2     598016                  // B*N
#define OFF_HAM1    606208                  // B*N
#define OFF_HMAAM2  614400                  // B*M
#define OFF_RMASK   615424                  // B*N (ints)
#define OFF_WAM3    623616                  // 16
#define OFF_HPRIME  623632                  // B*N*128 = 1048576
#define OFF_UPACK   1672208                 // B*N*32 u32 = 262144 words
#define OFF_OPMB    1934352                 // B*N*2 u64 = 32768 floats
// total ~1,967,120 floats ~ 7.9 MB

// ================= Kernel 1 (fused): h, h_ma, dots, rmask, opma bits, wam3,
//                   and adjacency bit-pack u = (op|op^T|ma|ma^T)>0 ===========
__global__ __launch_bounds__(256) void k1_prep(
    const float* __restrict__ x, const float* __restrict__ y,
    const int* __restrict__ op_ma_adj,
    const int* __restrict__ op_adj, const int* __restrict__ ma_adj,
    const float* __restrict__ w_op, const float* __restrict__ w_ma,
    const float* __restrict__ w_edge,
    const float* __restrict__ att_op, const float* __restrict__ att_ma,
    float* __restrict__ h, float* __restrict__ h_ma,
    float* __restrict__ ha1, float* __restrict__ ha2, float* __restrict__ ham1,
    float* __restrict__ hmaam2, int* __restrict__ rmask, float* __restrict__ wam3,
    unsigned* __restrict__ upack, unsigned long long* __restrict__ opmb)
{
    __shared__ float wlds[64 * 64];
    int bid = blockIdx.x;
    int t = threadIdx.x;
    int lane = t & 63;
    int wv = t >> 6;

    if (bid < 2048) {
        for (int k = t; k < 4096; k += 256) wlds[k] = w_op[k];
        __syncthreads();
        int row = bid * 4 + wv;                 // b*N + n, 0..8191
        float xv = x[(size_t)row * 64 + lane];
        float acc = 0.f;
        #pragma unroll
        for (int i = 0; i < 64; ++i) {
            float xi = __shfl(xv, i);
            acc += xi * wlds[i * 64 + lane];
        }
        h[(size_t)row * 64 + lane] = acc;
        float d1 = acc * att_op[lane];          // a1
        float d2 = acc * att_op[64 + lane];     // a2
        float d3 = acc * att_ma[lane];          // am1
        #pragma unroll
        for (int m = 32; m; m >>= 1) {
            d1 += __shfl_xor(d1, m);
            d2 += __shfl_xor(d2, m);
            d3 += __shfl_xor(d3, m);
        }
        int v0 = op_ma_adj[(size_t)row * 128 + lane];
        int v1 = op_ma_adj[(size_t)row * 128 + 64 + lane];
        unsigned long long w0 = __ballot(v0 != 0);
        unsigned long long w1 = __ballot(v1 != 0);
        if (lane == 0) {
            ha1[row] = d1; ha2[row] = d2; ham1[row] = d3;
            opmb[row * 2] = w0; opmb[row * 2 + 1] = w1;
            rmask[row] = ((w0 | w1) == 0ULL) ? 1 : 0;
        }
    } else if (bid < 2048 + 256) {
        for (int k = t; k < 4096; k += 256) wlds[k] = w_ma[k];
        __syncthreads();
        int row = (bid - 2048) * 4 + wv;        // b*M + m, 0..1023
        float yv = y[(size_t)row * 64 + lane];
        float acc = 0.f;
        #pragma unroll
        for (int i = 0; i < 64; ++i) {
            float yi = __shfl(yv, i);
            acc += yi * wlds[i * 64 + lane];
        }
        h_ma[(size_t)row * 64 + lane] = acc;
        float d = acc * att_ma[64 + lane];      // am2
        #pragma unroll
        for (int m = 32; m; m >>= 1) d += __shfl_xor(d, m);
        if (lane == 0) hmaam2[row] = d;
    } else if (bid == 2304) {
        if (t < 16) {
            float s = 0.f;
            for (int o = 0; o < 64; ++o) s += w_edge[t * 64 + o] * att_ma[128 + o];
            wam3[t] = s;
        }
    } else {
        // ---- adjacency bit-pack: tile pair (I,J), I<=J, per batch ----
        unsigned* sAB = (unsigned*)wlds;        // [2][64][2]
        int p = bid - 2305;                     // 0..1087
        int b = p / 136;
        int pr = p % 136;
        int I = 0;
        { int rem = pr, cnt = 16;
          while (rem >= cnt) { rem -= cnt; cnt--; I++; }
          pr = rem; }
        int J = I + pr;

        int c = t & 63, hr = (t >> 6) & 1, ts = t >> 7;
        int Ia = ts ? J : I, Ja = ts ? I : J;
        const int* opb = op_adj + (size_t)b * NN * NN + (size_t)(Ia * 64) * NN + Ja * 64;
        const int* mab = ma_adj + (size_t)b * NN * NN + (size_t)(Ia * 64) * NN + Ja * 64;
        unsigned w = 0;
        #pragma unroll 8
        for (int k = 0; k < 32; ++k) {
            int r = hr * 32 + k;
            int aval = opb[(size_t)r * NN + c] | mab[(size_t)r * NN + c];
            w |= (aval ? 1u : 0u) << k;
        }
        sAB[ts * 128 + c * 2 + hr] = w;
        __syncthreads();
        if (t < 128) {
            int r = t & 63, hh = t >> 6;
            int rw = r >> 5, rb = r & 31;
            unsigned dir1 = sAB[128 + r * 2 + hh];   // t2[c][r] bits
            unsigned dir2 = sAB[r * 2 + hh];         // t1[c][r] bits
            unsigned wt1 = 0, wt2 = 0;
            #pragma unroll 8
            for (int k = 0; k < 32; ++k) {
                int cc = hh * 32 + k;
                wt1 |= ((sAB[cc * 2 + rw] >> rb) & 1u) << k;        // t1[r][cc]
                wt2 |= ((sAB[128 + cc * 2 + rw] >> rb) & 1u) << k;  // t2[r][cc]
            }
            upack[((size_t)(b * NN + I * 64 + r)) * 32 + J * 2 + hh] = dir1 | wt1;
            upack[((size_t)(b * NN + J * 64 + r)) * 32 + I * 2 + hh] = dir2 | wt2;
        }
    }
}

// ================= Kernel 2: op attention + h_prime_op ======================
// block = 256 threads, one block per (b, 8-row tile).
__global__ __launch_bounds__(256) void k2_opatt(
    const unsigned* __restrict__ upack,
    const float* __restrict__ h, const float* __restrict__ ha1,
    const float* __restrict__ ha2, const int* __restrict__ rmask,
    float* __restrict__ h_prime)
{
    __shared__ float smem[8 * 1032];
    __shared__ float ha1s[1024];
    __shared__ unsigned uw[8 * 32];
    __shared__ float denom[8];
    int bid = blockIdx.x;
    int b = bid >> 7;
    int i0 = (bid & 127) * 8;
    int t = threadIdx.x;

    uw[t & 255] = upack[((size_t)(b * NN + i0)) * 32 + t];
    for (int k = t; k < 1024; k += 256) ha1s[k] = ha1[b * NN + k];
    __syncthreads();

    // phase 1: masked e, per-row max/sumexp, store unnormalized exp in LDS
    int ii = t >> 5, l = t & 31;
    int i = i0 + ii;
    float ha2i = ha2[b * NN + i];
    unsigned rm = rmask[b * NN + i] ? 0xFFFFFFFFu : 0u;
    float e[32];
    #pragma unroll
    for (int it = 0; it < 32; ++it) {
        int j = l + 32 * it;
        unsigned w = uw[ii * 32 + it] | rm;
        float ev = ha2i + ha1s[j];
        ev = ev > 0.f ? ev : 0.01f * ev;
        e[it] = ((w >> l) & 1u) ? ev : -INFINITY;
    }
    float mx = -INFINITY;
    #pragma unroll
    for (int it = 0; it < 32; ++it) mx = fmaxf(mx, e[it]);
    #pragma unroll
    for (int msk = 16; msk; msk >>= 1) mx = fmaxf(mx, __shfl_xor(mx, msk));
    float s = 0.f;
    #pragma unroll
    for (int it = 0; it < 32; ++it) {
        float u = __expf(e[it] - mx);
        smem[ii * 1032 + l + 32 * it] = u;
        s += u;
    }
    #pragma unroll
    for (int msk = 16; msk; msk >>= 1) s += __shfl_xor(s, msk);
    if (l == 0) denom[ii] = s;
    __syncthreads();

    // phase 2: h_prime_op[k][o] = sum_j u[k][j] * h[b][j][o]
    {
        int wv = t >> 6, o = t & 63;
        float acc[8];
        #pragma unroll
        for (int k = 0; k < 8; ++k) acc[k] = 0.f;
        const float* hb = h + (size_t)b * NN * 64;
        for (int jg = wv * 64; jg < wv * 64 + 64; ++jg) {
            int j = jg * 4;
            float h0 = hb[(size_t)(j + 0) * 64 + o];
            float h1 = hb[(size_t)(j + 1) * 64 + o];
            float h2 = hb[(size_t)(j + 2) * 64 + o];
            float h3 = hb[(size_t)(j + 3) * 64 + o];
            #pragma unroll
            for (int k = 0; k < 8; ++k) {
                float4 u4 = *(const float4*)&smem[k * 1032 + j];
                acc[k] += u4.x * h0 + u4.y * h1 + u4.z * h2 + u4.w * h3;
            }
        }
        __syncthreads();            // everyone done reading u
        #pragma unroll
        for (int k = 0; k < 8; ++k) smem[(wv * 8 + k) * 64 + o] = acc[k];
        __syncthreads();
        int oo = t & 63;
        int k0 = t >> 6;            // handles rows k0 and k0+4
        for (int kk = k0; kk < 8; kk += 4) {
            float v = smem[kk * 64 + oo] + smem[(8 + kk) * 64 + oo]
                    + smem[(16 + kk) * 64 + oo] + smem[(24 + kk) * 64 + oo];
            v /= denom[kk];
            h_prime[((size_t)(b * NN + i0 + kk)) * 128 + oo] = v;
        }
    }
}

// ================= Kernel 3: ma attention + h_prime_ma ======================
// block = 256 threads, handles 8 n's (2 at a time); h_ma staged in LDS.
__global__ __launch_bounds__(256) void k3_maatt(
    const float* __restrict__ z, const unsigned long long* __restrict__ opmb,
    const float* __restrict__ h, const float* __restrict__ h_ma,
    const float* __restrict__ ham1, const float* __restrict__ hmaam2,
    const int* __restrict__ rmask, const float* __restrict__ wam3,
    const float* __restrict__ w_edge, float* __restrict__ h_prime)
{
    __shared__ float hma_s[128 * 64];      // 32 KB
    __shared__ float u_s[2][128];
    __shared__ float redmx[4], redsm[4];
    __shared__ float part[2][8][16];
    __shared__ float zsum_s[2][16];
    __shared__ float hmp[2][2][64];
    __shared__ float wam3s[16];
    __shared__ float rdens[2];

    int bid = blockIdx.x;
    int b = bid >> 7;
    int n0 = (bid & 127) * 8;
    int t = threadIdx.x;
    int wvid = t >> 6;

    {
        const float4* src = (const float4*)(h_ma + (size_t)b * MM * 64);
        float4* dst = (float4*)hma_s;
        #pragma unroll
        for (int it = 0; it < 8; ++it) dst[t + 256 * it] = src[t + 256 * it];
    }
    if (t < 16) wam3s[t] = wam3[t];
    __syncthreads();

    for (int pp = 0; pp < 4; ++pp) {
        int nsel = t >> 7;
        int m = t & 127;
        int n = n0 + pp * 2 + nsel;
        int bn = b * NN + n;

        // ---- e / u ----
        size_t zbase = ((size_t)bn * MM + m) * 16;
        float4 z0 = *(const float4*)(z + zbase);
        float4 z1 = *(const float4*)(z + zbase + 4);
        float4 z2 = *(const float4*)(z + zbase + 8);
        float4 z3 = *(const float4*)(z + zbase + 12);
        float e = ham1[bn] + hmaam2[b * MM + m];
        e += z0.x*wam3s[0] + z0.y*wam3s[1] + z0.z*wam3s[2] + z0.w*wam3s[3];
        e += z1.x*wam3s[4] + z1.y*wam3s[5] + z1.z*wam3s[6] + z1.w*wam3s[7];
        e += z2.x*wam3s[8] + z2.y*wam3s[9] + z2.z*wam3s[10] + z2.w*wam3s[11];
        e += z3.x*wam3s[12] + z3.y*wam3s[13] + z3.z*wam3s[14] + z3.w*wam3s[15];
        e = e > 0.f ? e : 0.01f * e;
        unsigned long long bits = opmb[(size_t)bn * 2 + (m >> 6)];
        int valid = rmask[bn] | (int)((bits >> (m & 63)) & 1ULL);
        e = valid ? e : -INFINITY;

        float mx = e;
        #pragma unroll
        for (int msk = 32; msk; msk >>= 1) mx = fmaxf(mx, __shfl_xor(mx, msk));
        if ((t & 63) == 0) redmx[wvid] = mx;
        __syncthreads();
        mx = fmaxf(redmx[nsel * 2], redmx[nsel * 2 + 1]);
        float uu = __expf(e - mx);
        u_s[nsel][m] = uu;
        float sv = uu;
        #pragma unroll
        for (int msk = 32; msk; msk >>= 1) sv += __shfl_xor(sv, msk);
        if ((t & 63) == 0) redsm[wvid] = sv;
        __syncthreads();
        float den = redsm[nsel * 2] + redsm[nsel * 2 + 1];
        if (m == 0) rdens[nsel] = 1.f / den;

        // ---- zsum partials: thread = (nsel2, g, i) ----
        {
            int i = t & 15;
            int g = (t >> 4) & 7;
            int ns2 = t >> 7;
            int bn2 = b * NN + n0 + pp * 2 + ns2;
            const float* zr = z + (size_t)bn2 * MM * 16;
            float facc = 0.f;
            #pragma unroll
            for (int k = 0; k < 16; ++k) {
                int mm = g * 16 + k;
                facc += u_s[ns2][mm] * zr[(size_t)mm * 16 + i];
            }
            part[ns2][g][i] = facc;
        }
        // ---- h_ma matvec partials: thread = (nsel3, q, o) ----
        {
            int o = t & 63;
            int q = (t >> 6) & 1;
            int ns3 = t >> 7;
            float acc = 0.f;
            #pragma unroll 8
            for (int k = 0; k < 64; ++k) {
                int mm = q * 64 + k;
                acc += u_s[ns3][mm] * hma_s[mm * 64 + o];
            }
            hmp[ns3][q][o] = acc;
        }
        __syncthreads();
        if (t < 32) {
            int ns = t >> 4, i = t & 15;
            float zs = 0.f;
            #pragma unroll
            for (int g = 0; g < 8; ++g) zs += part[ns][g][i];
            zsum_s[ns][i] = zs;
        }
        __syncthreads();
        if (t < 128) {
            int ns = t >> 6, oo = t & 63;
            int bnf = b * NN + n0 + pp * 2 + ns;
            float he = 0.f;
            #pragma unroll
            for (int i = 0; i < 16; ++i) he += zsum_s[ns][i] * w_edge[i * 64 + oo];
            float val = (hmp[ns][0][oo] + hmp[ns][1][oo] + he) * rdens[ns]
                      + h[(size_t)bnf * 64 + oo];
            h_prime[(size_t)bnf * 128 + 64 + oo] = val;
        }
        __syncthreads();
    }
}

// ================= Kernel 4: MLP + final mask ===============================
__global__ __launch_bounds__(256) void k4_mlp(
    const float* __restrict__ hp, const int* __restrict__ rmask,
    const float* __restrict__ w1, const float* __restrict__ b1,
    const float* __restrict__ w2, const float* __restrict__ b2,
    const float* __restrict__ wo, const float* __restrict__ bo,
    float* __restrict__ out)
{
    int t = threadIdx.x, wv = t >> 6, o = t & 63;
    int row0 = blockIdx.x * 16 + wv * 4;

    float inlo[4], inhi[4];
    #pragma unroll
    for (int r = 0; r < 4; ++r) {
        inlo[r] = hp[(size_t)(row0 + r) * 128 + o];
        inhi[r] = hp[(size_t)(row0 + r) * 128 + 64 + o];
    }
    float t1lo[4], t1hi[4];
    {
        float blo = b1[o], bhi = b1[64 + o];
        #pragma unroll
        for (int r = 0; r < 4; ++r) { t1lo[r] = blo; t1hi[r] = bhi; }
        for (int i = 0; i < 64; ++i) {
            float wl = w1[i * 128 + o], wh = w1[i * 128 + 64 + o];
            #pragma unroll
            for (int r = 0; r < 4; ++r) {
                float xi = __shfl(inlo[r], i);
                t1lo[r] += xi * wl; t1hi[r] += xi * wh;
            }
        }
        for (int i = 0; i < 64; ++i) {
            float wl = w1[(64 + i) * 128 + o], wh = w1[(64 + i) * 128 + 64 + o];
            #pragma unroll
            for (int r = 0; r < 4; ++r) {
                float xi = __shfl(inhi[r], i);
                t1lo[r] += xi * wl; t1hi[r] += xi * wh;
            }
        }
        #pragma unroll
        for (int r = 0; r < 4; ++r) {
            t1lo[r] = t1lo[r] > 0.f ? t1lo[r] : __expf(t1lo[r]) - 1.f;
            t1hi[r] = t1hi[r] > 0.f ? t1hi[r] : __expf(t1hi[r]) - 1.f;
        }
    }
    float t2lo[4], t2hi[4];
    {
        float blo = b2[o], bhi = b2[64 + o];
        #pragma unroll
        for (int r = 0; r < 4; ++r) { t2lo[r] = blo; t2hi[r] = bhi; }
        for (int i = 0; i < 64; ++i) {
            float wl = w2[i * 128 + o], wh = w2[i * 128 + 64 + o];
            #pragma unroll
            for (int r = 0; r < 4; ++r) {
                float xi = __shfl(t1lo[r], i);
                t2lo[r] += xi * wl; t2hi[r] += xi * wh;
            }
        }
        for (int i = 0; i < 64; ++i) {
            float wl = w2[(64 + i) * 128 + o], wh = w2[(64 + i) * 128 + 64 + o];
            #pragma unroll
            for (int r = 0; r < 4; ++r) {
                float xi = __shfl(t1hi[r], i);
                t2lo[r] += xi * wl; t2hi[r] += xi * wh;
            }
        }
        #pragma unroll
        for (int r = 0; r < 4; ++r) {
            t2lo[r] = t2lo[r] > 0.f ? t2lo[r] : __expf(t2lo[r]) - 1.f;
            t2hi[r] = t2hi[r] > 0.f ? t2hi[r] : __expf(t2hi[r]) - 1.f;
        }
    }
    float acc[4];
    {
        float bov = bo[o];
        #pragma unroll
        for (int r = 0; r < 4; ++r) acc[r] = bov;
        for (int i = 0; i < 64; ++i) {
            float wl = wo[i * 64 + o];
            #pragma unroll
            for (int r = 0; r < 4; ++r) acc[r] += __shfl(t2lo[r], i) * wl;
        }
        for (int i = 0; i < 64; ++i) {
            float wl = wo[(64 + i) * 64 + o];
            #pragma unroll
            for (int r = 0; r < 4; ++r) acc[r] += __shfl(t2hi[r], i) * wl;
        }
    }
    #pragma unroll
    for (int r = 0; r < 4; ++r) {
        int row = row0 + r;
        float v = rmask[row] ? 0.f : acc[r];
        out[(size_t)row * 64 + o] = v;
    }
}

// ============================ launch ========================================
extern "C" void kernel_launch(void* const* d_in, const int* in_sizes, int n_in,
                              void* d_out, int out_size, void* d_ws, size_t ws_size,
                              hipStream_t stream) {
    const float* x      = (const float*)d_in[0];
    const float* y      = (const float*)d_in[1];
    const float* z      = (const float*)d_in[2];
    const int*   op_adj = (const int*)d_in[3];
    const int*   ma_adj = (const int*)d_in[4];
    const int*   opma   = (const int*)d_in[5];
    const float* w_op   = (const float*)d_in[6];
    const float* w_ma   = (const float*)d_in[7];
    const float* w_edge = (const float*)d_in[8];
    const float* att_op = (const float*)d_in[9];
    const float* att_ma = (const float*)d_in[10];
    const float* w1     = (const float*)d_in[11];
    const float* b1     = (const float*)d_in[12];
    const float* w2     = (const float*)d_in[13];
    const float* b2     = (const float*)d_in[14];
    const float* wo     = (const float*)d_in[15];
    const float* bo     = (const float*)d_in[16];
    float* out = (float*)d_out;

    float* ws = (float*)d_ws;
    float* h       = ws + OFF_H;
    float* h_ma    = ws + OFF_HMA;
    float* ha1     = ws + OFF_HA1;
    float* ha2     = ws + OFF_HA2;
    float* ham1    = ws + OFF_HAM1;
    float* hmaam2  = ws + OFF_HMAAM2;
    int*   rmask   = (int*)(ws + OFF_RMASK);
    float* wam3    = ws + OFF_WAM3;
    float* h_prime = ws + OFF_HPRIME;
    unsigned* upack = (unsigned*)(ws + OFF_UPACK);
    unsigned long long* opmb = (unsigned long long*)(ws + OFF_OPMB);

    k1_prep<<<2048 + 256 + 1 + 1088, 256, 0, stream>>>(
        x, y, opma, op_adj, ma_adj, w_op, w_ma, w_edge, att_op, att_ma,
        h, h_ma, ha1, ha2, ham1, hmaam2, rmask, wam3, upack, opmb);

    k2_opatt<<<1024, 256, 0, stream>>>(
        upack, h, ha1, ha2, rmask, h_prime);

    k3_maatt<<<1024, 256, 0, stream>>>(
        z, opmb, h, h_ma, ham1, hmaam2, rmask, wam3, w_edge, h_prime);

    k4_mlp<<<512, 256, 0, stream>>>(
        h_prime, rmask, w1, b1, w2, b2, wo, bo, out);
}